// Round 5
// baseline (470.291 us; speedup 1.0000x reference)
//
#include <hip/hip_runtime.h>

// Fused LSTM(H=128) + 3-layer MLP head, bf16 MFMA (16x16x32), fp32 state.
// B=8192 rows, T=30 steps. 512 blocks x 256 threads (4 waves), 16 rows/block
// => 2 INDEPENDENT blocks/CU (the r0-r4 lesson): 2 waves/SIMD from DIFFERENT
// workgroups, so one block's MFMA/VALU overlaps the other block's barrier
// drains + LDS latency + transcendental chains. (r3 had 2 waves/SIMD from the
// SAME 8-wave block -> lockstep at all 6 barriers/step. r4's (512,4) 128-reg
// cap spilled: VGPR 64, FETCH 794MB, 346us.)
// REGISTER BUDGET (gfx950 unified file, accum allocated on top of arch VGPRs):
//  resident Bzh[4g][4ks][2n] = 128 VGPR; x/B1/B2 frags streamed from the
//  L2-resident 224KB pack each step (r4-proven mechanics, opaque-ptr asm
//  defeats LICM re-hoisting); peak ~ 128+32 in-flight+~25 work arch + ~48
//  accum ~= 233 <= (256,2)'s 256 cap. Failure signature if wrong: FETCH_SIZE
//  explosion + scratch fillBuffer dispatch.
// - Wave w owns col-tiles 2w,2w+1 (cols [32w,32w+32)); z-GEMM N-tiles at
//   g*128+(2w+n)*16 => (i,f,g,o) quadruple + c-state in-lane.
// - x-kstep packs x_hi (k0..7) | x_lo (k8..15), Wi replicated in the B-frag.
// - h/o1 B-frags used for both hi and lo A-panels (same weights).
// - 16x16x32 layouts: A/B: row|col=lane&15, k=(lane>>4)*8+j; C/D: col=lane&15,
//   row=(lane>>4)*4+reg (m89-verified).
// - A-panels [16 rows][40 shorts] (32 data + 8 pad): 16B-aligned b128 reads.
// - Precision identical to passing config: hi/lo split x,h; single-bf16 o1;
//   fp32 acc, gates, o2, head, feedback.

#define T_STEPS 30
#define WARM_N  24

typedef __attribute__((ext_vector_type(8)))  short short8;   // 8 bf16 = 4 VGPRs
typedef __attribute__((ext_vector_type(4)))  float float4v;  // MFMA 16x16 C/D

struct FeatPtrs { const float* f[7]; };

__device__ __forceinline__ short f2bf(float f){
  unsigned u = __float_as_uint(f);
  unsigned r = (u + 0x7fffu + ((u >> 16) & 1u)) >> 16;   // round-nearest-even
  return (short)r;
}
__device__ __forceinline__ float bf2f(short h){
  return __uint_as_float(((unsigned)(unsigned short)h) << 16);
}

#if __has_builtin(__builtin_amdgcn_rcpf)
#define RCP(x) __builtin_amdgcn_rcpf(x)
#else
#define RCP(x) (1.0f/(x))
#endif

__device__ __forceinline__ float sigm(float x){ return RCP(1.0f + __expf(-x)); }
__device__ __forceinline__ float tanh_(float x){ return 1.0f - 2.0f*RCP(1.0f + __expf(2.0f*x)); }

// ---------------- weight pack kernel ----------------
// 224 frags of 512 bf16 (1 KB each), frag elem (lane,j):
//   col16 = lane&15, kk = (lane>>4)*8 + j  (K=32 per fragment)
// frags 0..159 : z-weights [wt 0..7][g 0..3][ks 0..4]
//   ks=0: x-frag: kk<8 -> Wi[kk][col], kk 8..15 -> Wi[kk-8][col] (lo replica),
//         kk>=16 -> 0;  ks 1..4: Wh[(ks-1)*32+kk][col];  col = g*128+wt*16+col16
// frags 160..191: W1 [wt][ks 0..3]: W1[ks*32+kk][wt*16+col16]
// frags 192..223: W2 same layout.
__global__ void pack_weights(const float* __restrict__ Wi, const float* __restrict__ Wh,
                             const float* __restrict__ W1, const float* __restrict__ W2,
                             short* __restrict__ ws)
{
  int idx = blockIdx.x * 256 + threadIdx.x;
  if (idx >= 224 * 512) return;
  int f    = idx >> 9;
  int r    = idx & 511;
  int lane = r >> 3, j = r & 7;
  int kk   = ((lane >> 4) << 3) + j;     // 0..31
  int c16  = lane & 15;
  float v = 0.0f;
  if (f < 160){
    int wt = f / 20, rem = f % 20, g = rem / 5, ks = rem % 5;
    int col = g * 128 + wt * 16 + c16;
    if (ks == 0){
      if (kk < 8)        v = Wi[kk * 512 + col];
      else if (kk < 16)  v = Wi[(kk - 8) * 512 + col];
      else               v = 0.0f;
    } else {
      v = Wh[((ks - 1) * 32 + kk) * 512 + col];
    }
  } else {
    int f2 = f - 160;                    // 0..63
    const float* W = (f2 < 32) ? W1 : W2;
    int f3 = f2 & 31;
    int wt = f3 >> 2, ks = f3 & 3;
    v = W[(ks * 32 + kk) * 128 + wt * 16 + c16];
  }
  ws[idx] = f2bf(v);
}

// ---------------- main kernel ----------------
__global__ __launch_bounds__(256, 2)
void lstm_mfma(FeatPtrs fp, const float* __restrict__ irr,
               const short* __restrict__ wsb,
               const float* __restrict__ bz, const float* __restrict__ b1,
               const float* __restrict__ b2, const float* __restrict__ Wout,
               const float* __restrict__ bout, float* __restrict__ out)
{
  // A-panels: [kstep][16 rows][40 shorts] (k 0..31 data + 8 pad)
  __shared__ __align__(16) short xp [640];          // x: k0..7 hi, k8..15 lo
  __shared__ __align__(16) short hhi[4 * 640];      // h hi, 4 ksteps
  __shared__ __align__(16) short hlo[4 * 640];      // h lo
  __shared__ __align__(16) short o1p[4 * 640];      // o1 single bf16
  __shared__ __align__(16) float o2s[16 * 132];     // o2 fp32, padded rows
  __shared__ float WoutS[128];
  __shared__ float pS[16];

  const int t   = threadIdx.x;
  const int l   = t & 63;
  const int w   = t >> 6;        // wave 0..3, owns col-tiles 2w and 2w+1
  const int c16 = l & 15;
  const int kq  = l >> 4;        // 0..3
  const int r0  = blockIdx.x * 16;

  const short8* f8 = (const short8*)wsb;

  // resident weights: only the 32 Wh fragments (128 VGPRs)
  short8 Bzh[4][4][2];
#pragma unroll
  for (int g = 0; g < 4; ++g)
#pragma unroll
    for (int ks = 0; ks < 4; ++ks)
#pragma unroll
      for (int n = 0; n < 2; ++n)
        Bzh[g][ks][n] = f8[(((2 * w + n) * 4 + g) * 5 + 1 + ks) * 64 + l];

  float bzv[4][2];
#pragma unroll
  for (int g = 0; g < 4; ++g)
#pragma unroll
    for (int n = 0; n < 2; ++n)
      bzv[g][n] = bz[g * 128 + (2 * w + n) * 16 + c16];
  float b1v[2], b2v[2];
#pragma unroll
  for (int n = 0; n < 2; ++n){
    b1v[n] = b1[(2 * w + n) * 16 + c16];
    b2v[n] = b2[(2 * w + n) * 16 + c16];
  }
  const float bout0 = bout[0];
  if (t < 128) WoutS[t] = Wout[t];

  { // zero x panel (k16..31 must stay 0) and h panels (h0 = 0)
    int* p = (int*)xp;
    for (int i = t; i < 320;  i += 256) p[i] = 0;
    p = (int*)hhi;
    for (int i = t; i < 1280; i += 256) p[i] = 0;
    p = (int*)hlo;
    for (int i = t; i < 1280; i += 256) p[i] = 0;
  }

  float cst[8];                            // [n*4+r]
#pragma unroll
  for (int i = 0; i < 8; ++i) cst[i] = 0.0f;

  const int aoff = c16 * 40 + kq * 8;      // A-frag read offset (shorts)
  // h/o1 write base per n-tile: col=(2w+n)*16+c16 -> kstep w, k-in-step n*16+c16
  const int wb0 = w * 640 + c16;
  const int wb1 = w * 640 + 16 + c16;
  __syncthreads();

  for (int step = 0; step < T_STEPS; ++step){
    // ---- stream x-frags for this step (opaque ptr defeats LICM; loads
    //      issue here, land during gather+barrier+h-MFMAs, used at z end) ----
    const short8* fx = f8;
    asm volatile("" : "+v"(fx));
    short8 Bzx[4][2];
#pragma unroll
    for (int g = 0; g < 4; ++g)
#pragma unroll
      for (int n = 0; n < 2; ++n)
        Bzx[g][n] = fx[(((2 * w + n) * 4 + g) * 5) * 64 + l];

    if (t < 128){ // ---- gather 8 input features for 16 rows, split hi/lo ----
      int r = t >> 3, j = t & 7;
      float v;
      if (j < 7)               v = fp.f[j][(r0 + r) * T_STEPS + step];
      else if (step < WARM_N)  v = irr[(r0 + r) * WARM_N + step];
      else                     v = pS[r];               // autoregressive feedback
      int base = r * 40 + j;
      short hi = f2bf(v);
      xp[base]     = hi;
      xp[base + 8] = f2bf(v - bf2f(hi));
    }
    __syncthreads();

    // ---- z = b + [h_hi+h_lo]@Wh + x@Wi  (4 gates x 2 N-tiles in-lane) ----
    float4v acc[4][2];
#pragma unroll
    for (int g = 0; g < 4; ++g)
#pragma unroll
      for (int n = 0; n < 2; ++n)
#pragma unroll
        for (int r = 0; r < 4; ++r) acc[g][n][r] = bzv[g][n];
#pragma unroll
    for (int ks = 0; ks < 4; ++ks){
      short8 ah = *(const short8*)&hhi[ks * 640 + aoff];
      short8 al = *(const short8*)&hlo[ks * 640 + aoff];
#pragma unroll
      for (int g = 0; g < 4; ++g)
#pragma unroll
        for (int n = 0; n < 2; ++n){
          acc[g][n] = __builtin_amdgcn_mfma_f32_16x16x32_bf16(ah, Bzh[g][ks][n], acc[g][n], 0, 0, 0);
          acc[g][n] = __builtin_amdgcn_mfma_f32_16x16x32_bf16(al, Bzh[g][ks][n], acc[g][n], 0, 0, 0);
        }
    }
    {
      short8 ax = *(const short8*)&xp[aoff];
#pragma unroll
      for (int g = 0; g < 4; ++g)
#pragma unroll
        for (int n = 0; n < 2; ++n)
          acc[g][n] = __builtin_amdgcn_mfma_f32_16x16x32_bf16(ax, Bzx[g][n], acc[g][n], 0, 0, 0);
    }
    __syncthreads();   // all panel reads done before h rewrite

    // ---- stream B1 frags (land during gates epilogue + barrier) ----
    const short8* f1 = f8;
    asm volatile("" : "+v"(f1));
    short8 B1f[2][4];
#pragma unroll
    for (int n = 0; n < 2; ++n)
#pragma unroll
      for (int ks = 0; ks < 4; ++ks)
        B1f[n][ks] = f1[(160 + (2 * w + n) * 4 + ks) * 64 + l];

    // ---- gates (fp32, in-lane), update c, write h hi/lo panels ----
#pragma unroll
    for (int n = 0; n < 2; ++n)
#pragma unroll
      for (int r = 0; r < 4; ++r){
        float zi = acc[0][n][r], zf = acc[1][n][r], zg = acc[2][n][r], zo = acc[3][n][r];
        float c2 = sigm(zf) * cst[n * 4 + r] + sigm(zi) * tanh_(zg);
        cst[n * 4 + r] = c2;
        float h2 = sigm(zo) * tanh_(c2);
        int addr = (n ? wb1 : wb0) + (kq * 4 + r) * 40;   // row = kq*4+r (C/D map)
        short hi = f2bf(h2);
        hhi[addr] = hi;
        hlo[addr] = f2bf(h2 - bf2f(hi));
      }
    __syncthreads();

    // ---- MLP1: o1 = relu(h@W1 + b1) ----
    float4v m1[2];
#pragma unroll
    for (int n = 0; n < 2; ++n)
#pragma unroll
      for (int r = 0; r < 4; ++r) m1[n][r] = b1v[n];
#pragma unroll
    for (int ks = 0; ks < 4; ++ks){
      short8 ah = *(const short8*)&hhi[ks * 640 + aoff];
      short8 al = *(const short8*)&hlo[ks * 640 + aoff];
#pragma unroll
      for (int n = 0; n < 2; ++n){
        m1[n] = __builtin_amdgcn_mfma_f32_16x16x32_bf16(ah, B1f[n][ks], m1[n], 0, 0, 0);
        m1[n] = __builtin_amdgcn_mfma_f32_16x16x32_bf16(al, B1f[n][ks], m1[n], 0, 0, 0);
      }
    }

    // ---- stream B2 frags (B1 now dead; land during o1 write + barrier) ----
    const short8* f2p = f8;
    asm volatile("" : "+v"(f2p));
    short8 B2f[2][4];
#pragma unroll
    for (int n = 0; n < 2; ++n)
#pragma unroll
      for (int ks = 0; ks < 4; ++ks)
        B2f[n][ks] = f2p[(192 + (2 * w + n) * 4 + ks) * 64 + l];

#pragma unroll
    for (int n = 0; n < 2; ++n)
#pragma unroll
      for (int r = 0; r < 4; ++r){
        int addr = (n ? wb1 : wb0) + (kq * 4 + r) * 40;
        o1p[addr] = f2bf(fmaxf(m1[n][r], 0.0f));
      }
    __syncthreads();

    // ---- MLP2: o2 = relu(o1@W2 + b2), store fp32 ----
    float4v m2[2];
#pragma unroll
    for (int n = 0; n < 2; ++n)
#pragma unroll
      for (int r = 0; r < 4; ++r) m2[n][r] = b2v[n];
#pragma unroll
    for (int ks = 0; ks < 4; ++ks){
      short8 a = *(const short8*)&o1p[ks * 640 + aoff];
#pragma unroll
      for (int n = 0; n < 2; ++n)
        m2[n] = __builtin_amdgcn_mfma_f32_16x16x32_bf16(a, B2f[n][ks], m2[n], 0, 0, 0);
    }
#pragma unroll
    for (int n = 0; n < 2; ++n)
#pragma unroll
      for (int r = 0; r < 4; ++r)
        o2s[(kq * 4 + r) * 132 + (2 * w + n) * 16 + c16] = fmaxf(m2[n][r], 0.0f);
    __syncthreads();

    // ---- head: p = o2 . Wout + bout (fp32 exact), 8 threads/row ----
    if (t < 128){
      int r = t >> 3, jj = t & 7;
      const float* orow = &o2s[r * 132 + jj * 16];
      const float* wrow = &WoutS[jj * 16];
      float s = 0.0f;
#pragma unroll
      for (int q = 0; q < 16; ++q) s += orow[q] * wrow[q];
      s += __shfl_down(s, 4, 8);
      s += __shfl_down(s, 2, 8);
      s += __shfl_down(s, 1, 8);
      if (jj == 0){
        float p = s + bout0;
        out[(r0 + r) * T_STEPS + step] = p;
        pS[r] = p;
      }
    }
    __syncthreads();   // pS/panels visible before next step
  }
}

extern "C" void kernel_launch(void* const* d_in, const int* in_sizes, int n_in,
                              void* d_out, int out_size, void* d_ws, size_t ws_size,
                              hipStream_t stream)
{
  (void)in_sizes; (void)n_in; (void)out_size; (void)ws_size;
  // inputs: 0..7 weather (unused), 8..14 time feats, 15 irradiance_in,
  // 16 Wi, 17 Wh, 18 b, 19 W1, 20 b1, 21 W2, 22 b2, 23 Wout, 24 bout
  FeatPtrs fp;
  for (int j = 0; j < 7; ++j) fp.f[j] = (const float*)d_in[8 + j];
  const float* irr  = (const float*)d_in[15];
  const float* Wi   = (const float*)d_in[16];
  const float* Wh   = (const float*)d_in[17];
  const float* bz   = (const float*)d_in[18];
  const float* W1   = (const float*)d_in[19];
  const float* b1   = (const float*)d_in[20];
  const float* W2   = (const float*)d_in[21];
  const float* b2   = (const float*)d_in[22];
  const float* Wout = (const float*)d_in[23];
  const float* bout = (const float*)d_in[24];

  short* ws = (short*)d_ws;                       // 224*512*2 = 224 KB used
  pack_weights<<<dim3(448), dim3(256), 0, stream>>>(Wi, Wh, W1, W2, ws);
  lstm_mfma<<<dim3(512), dim3(256), 0, stream>>>(
      fp, irr, ws, bz, b1, b2, Wout, bout, (float*)d_out);
}

// Round 6
// 205.752 us; speedup vs baseline: 2.2857x; 2.2857x over previous
//
#include <hip/hip_runtime.h>

// Fused LSTM(H=128) + 3-layer MLP head, bf16 MFMA (16x16x32), fp32 state.
// B=8192 rows, T=30 steps. 256 blocks x 512 threads (8 waves), 32 rows/block.
// BASE = round-3 kernel (141us, 124 VGPR, 2 waves/SIMD, no spill). Rounds 4/5
// proved 4 waves/SIMD is register-infeasible (streamed-weight variants spilled:
// FETCH 0.7-1.4 GB). This round keeps r3's resources and attacks PHASE
// SERIALIZATION instead:
//   Warm steps (0..23) don't need the p feedback (gather reads irr), so the
//   MLP+head is off the recurrence critical path. Software-pipeline it:
//     iter i, phase A: gather(i+1) | z-GEMM(i) | MLP1(i-1) fused on the SAME
//                      h-panel ds_reads | head(i-2)        (MFMA+VALU mixed)
//     iter i, phase B: gates(i) | MLP2(i-1)                (VALU+MFMA mixed)
//   => 2 barriers/iter instead of 6, both pipes busy in each region, and
//   MLP1's 8 ds_read_b128/wave are free (shared with z).
//   Steps 23..29 run the serial r3 body (p feedback chain forces it).
// Accumulation order per accumulator is preserved exactly -> bit-identical.
// Register budget: r3 resident set (Bz 80 + B1f 16 + B2f 16 = 112 VGPR) + acc
// 32 + m1 8 live in phase A; peak ~196 < (512,2)'s 256 cap.
// - Wave w owns output cols [16w,16w+16); 2 M-tiles (rows 0-15,16-31).
// - x-kstep packs x_hi (k0..7) | x_lo (k8..15), Wi replicated in the B-frag.
// - 16x16x32 layouts: A/B: row|col=lane&15, k=(lane>>4)*8+j; C/D: col=lane&15,
//   row=(lane>>4)*4+reg (m89-verified).
// - A-panels [16 rows][40 shorts] (32 data + 8 pad): 16B-aligned b128 reads.
// - Precision identical: hi/lo split x,h; single-bf16 o1; fp32 acc/gates/head.

#define T_STEPS 30
#define WARM_N  24

typedef __attribute__((ext_vector_type(8)))  short short8;   // 8 bf16 = 4 VGPRs
typedef __attribute__((ext_vector_type(4)))  float float4v;  // MFMA 16x16 C/D

struct FeatPtrs { const float* f[7]; };

__device__ __forceinline__ short f2bf(float f){
  unsigned u = __float_as_uint(f);
  unsigned r = (u + 0x7fffu + ((u >> 16) & 1u)) >> 16;   // round-nearest-even
  return (short)r;
}
__device__ __forceinline__ float bf2f(short h){
  return __uint_as_float(((unsigned)(unsigned short)h) << 16);
}

#if __has_builtin(__builtin_amdgcn_rcpf)
#define RCP(x) __builtin_amdgcn_rcpf(x)
#else
#define RCP(x) (1.0f/(x))
#endif

__device__ __forceinline__ float sigm(float x){ return RCP(1.0f + __expf(-x)); }
__device__ __forceinline__ float tanh_(float x){ return 1.0f - 2.0f*RCP(1.0f + __expf(2.0f*x)); }

// ---------------- weight pack kernel ----------------
// 224 frags of 512 bf16 (1 KB each), frag elem (lane,j):
//   col16 = lane&15, kk = (lane>>4)*8 + j  (K=32 per fragment)
// frags 0..159 : z-weights [wt 0..7][g 0..3][ks 0..4]
//   ks=0: x-frag: kk<8 -> Wi[kk][col], kk 8..15 -> Wi[kk-8][col] (lo replica),
//         kk>=16 -> 0;  ks 1..4: Wh[(ks-1)*32+kk][col];  col = g*128+wt*16+col16
// frags 160..191: W1 [wt][ks 0..3]: W1[ks*32+kk][wt*16+col16]
// frags 192..223: W2 same layout.
__global__ void pack_weights(const float* __restrict__ Wi, const float* __restrict__ Wh,
                             const float* __restrict__ W1, const float* __restrict__ W2,
                             short* __restrict__ ws)
{
  int idx = blockIdx.x * 256 + threadIdx.x;
  if (idx >= 224 * 512) return;
  int f    = idx >> 9;
  int r    = idx & 511;
  int lane = r >> 3, j = r & 7;
  int kk   = ((lane >> 4) << 3) + j;     // 0..31
  int c16  = lane & 15;
  float v = 0.0f;
  if (f < 160){
    int wt = f / 20, rem = f % 20, g = rem / 5, ks = rem % 5;
    int col = g * 128 + wt * 16 + c16;
    if (ks == 0){
      if (kk < 8)        v = Wi[kk * 512 + col];
      else if (kk < 16)  v = Wi[(kk - 8) * 512 + col];
      else               v = 0.0f;
    } else {
      v = Wh[((ks - 1) * 32 + kk) * 512 + col];
    }
  } else {
    int f2 = f - 160;                    // 0..63
    const float* W = (f2 < 32) ? W1 : W2;
    int f3 = f2 & 31;
    int wt = f3 >> 2, ks = f3 & 3;
    v = W[(ks * 32 + kk) * 128 + wt * 16 + c16];
  }
  ws[idx] = f2bf(v);
}

// ---------------- main kernel ----------------
__global__ __launch_bounds__(512, 2)
void lstm_mfma(FeatPtrs fp, const float* __restrict__ irr,
               const short* __restrict__ wsb,
               const float* __restrict__ bz, const float* __restrict__ b1,
               const float* __restrict__ b2, const float* __restrict__ Wout,
               const float* __restrict__ bout, float* __restrict__ out)
{
  // A-panels: [kstep][m-tile 0..1][16 rows][40 shorts] (k 0..31 data + 8 pad)
  __shared__ __align__(16) short xp[2][1280];       // x, DOUBLE-buffered steps
  __shared__ __align__(16) short hhi[4 * 1280];     // h hi, 4 ksteps
  __shared__ __align__(16) short hlo[4 * 1280];     // h lo
  __shared__ __align__(16) short o1p[4 * 1280];     // o1 single bf16
  __shared__ __align__(16) float o2s[32 * 132];     // o2 fp32, padded rows
  __shared__ float WoutS[128];
  __shared__ float pS[32];

  const int t   = threadIdx.x;
  const int l   = t & 63;
  const int w   = t >> 6;        // wave 0..7, owns cols [16w,16w+16)
  const int c16 = l & 15;
  const int kq  = l >> 4;        // 0..3
  const int r0  = blockIdx.x * 32;

  // weight fragments -> registers (coalesced dwordx4 loads)
  short8 Bz[4][5], B1f[4], B2f[4];
  {
    const short8* f8 = (const short8*)wsb;
#pragma unroll
    for (int g = 0; g < 4; ++g)
#pragma unroll
      for (int ks = 0; ks < 5; ++ks)
        Bz[g][ks] = f8[((w * 4 + g) * 5 + ks) * 64 + l];
#pragma unroll
    for (int ks = 0; ks < 4; ++ks) B1f[ks] = f8[(160 + w * 4 + ks) * 64 + l];
#pragma unroll
    for (int ks = 0; ks < 4; ++ks) B2f[ks] = f8[(192 + w * 4 + ks) * 64 + l];
  }
  float bzv[4];
#pragma unroll
  for (int g = 0; g < 4; ++g) bzv[g] = bz[g * 128 + w * 16 + c16];
  const float b1v   = b1[w * 16 + c16];
  const float b2v   = b2[w * 16 + c16];
  const float bout0 = bout[0];
  if (t < 128) WoutS[t] = Wout[t];

  { // zero x buffers (k16..31 pad must stay 0) and h panels (h0 = 0)
    int* p = (int*)xp;
    for (int i = t; i < 1280; i += 512) p[i] = 0;
    p = (int*)hhi;
    for (int i = t; i < 2560; i += 512) p[i] = 0;
    p = (int*)hlo;
    for (int i = t; i < 2560; i += 512) p[i] = 0;
  }

  float cst[8];
#pragma unroll
  for (int i = 0; i < 8; ++i) cst[i] = 0.0f;

  const int aoff = c16 * 40 + kq * 8;                    // A-frag read offset
  const int wb   = (w >> 1) * 1280 + (w & 1) * 16 + c16; // h/o1 write base
  __syncthreads();

  // prologue: gather step 0 into xp[0]
  if (t < 256){
    int r = t >> 3, j = t & 7;
    float v = (j < 7) ? fp.f[j][(r0 + r) * T_STEPS] : irr[(r0 + r) * WARM_N];
    int base = (r >> 4) * 640 + (r & 15) * 40 + j;
    short hi = f2bf(v);
    xp[0][base] = hi;
    xp[0][base + 8] = f2bf(v - bf2f(hi));
  }
  __syncthreads();

  // =================== pipelined warm loop: i = 0..22 ===================
  for (int i = 0; i < 23; ++i){
    // ---------------- PHASE A ----------------
    // gather(i+1) (i+1 <= 23 < WARM_N: always irr for j==7)
    if (t < 256){
      int r = t >> 3, j = t & 7;
      float v = (j < 7) ? fp.f[j][(r0 + r) * T_STEPS + (i + 1)]
                        : irr[(r0 + r) * WARM_N + (i + 1)];
      int base = (r >> 4) * 640 + (r & 15) * 40 + j;
      short hi = f2bf(v);
      short* xb = xp[(i + 1) & 1];
      xb[base] = hi;
      xb[base + 8] = f2bf(v - bf2f(hi));
    }
    // z(i) + MLP1(i-1), fused on shared h-panel reads
    float4v acc[4][2];
#pragma unroll
    for (int g = 0; g < 4; ++g)
#pragma unroll
      for (int m = 0; m < 2; ++m)
#pragma unroll
        for (int r = 0; r < 4; ++r) acc[g][m][r] = bzv[g];
    float4v m1[2];
#pragma unroll
    for (int m = 0; m < 2; ++m)
#pragma unroll
      for (int r = 0; r < 4; ++r) m1[m][r] = b1v;
    {
      const short* xb = xp[i & 1];
      short8 a0 = *(const short8*)&xb[aoff];
      short8 a1 = *(const short8*)&xb[640 + aoff];
#pragma unroll
      for (int g = 0; g < 4; ++g){
        acc[g][0] = __builtin_amdgcn_mfma_f32_16x16x32_bf16(a0, Bz[g][0], acc[g][0], 0, 0, 0);
        acc[g][1] = __builtin_amdgcn_mfma_f32_16x16x32_bf16(a1, Bz[g][0], acc[g][1], 0, 0, 0);
      }
    }
#pragma unroll
    for (int ks = 0; ks < 4; ++ks){
      short8 ah0 = *(const short8*)&hhi[ks * 1280 + aoff];
      short8 al0 = *(const short8*)&hlo[ks * 1280 + aoff];
      short8 ah1 = *(const short8*)&hhi[ks * 1280 + 640 + aoff];
      short8 al1 = *(const short8*)&hlo[ks * 1280 + 640 + aoff];
#pragma unroll
      for (int g = 0; g < 4; ++g){
        acc[g][0] = __builtin_amdgcn_mfma_f32_16x16x32_bf16(ah0, Bz[g][1 + ks], acc[g][0], 0, 0, 0);
        acc[g][0] = __builtin_amdgcn_mfma_f32_16x16x32_bf16(al0, Bz[g][1 + ks], acc[g][0], 0, 0, 0);
        acc[g][1] = __builtin_amdgcn_mfma_f32_16x16x32_bf16(ah1, Bz[g][1 + ks], acc[g][1], 0, 0, 0);
        acc[g][1] = __builtin_amdgcn_mfma_f32_16x16x32_bf16(al1, Bz[g][1 + ks], acc[g][1], 0, 0, 0);
      }
      if (i >= 1){
        m1[0] = __builtin_amdgcn_mfma_f32_16x16x32_bf16(ah0, B1f[ks], m1[0], 0, 0, 0);
        m1[0] = __builtin_amdgcn_mfma_f32_16x16x32_bf16(al0, B1f[ks], m1[0], 0, 0, 0);
        m1[1] = __builtin_amdgcn_mfma_f32_16x16x32_bf16(ah1, B1f[ks], m1[1], 0, 0, 0);
        m1[1] = __builtin_amdgcn_mfma_f32_16x16x32_bf16(al1, B1f[ks], m1[1], 0, 0, 0);
      }
    }
    if (i >= 1){ // write o1p(i-1)
#pragma unroll
      for (int m = 0; m < 2; ++m)
#pragma unroll
        for (int r = 0; r < 4; ++r)
          o1p[wb + m * 640 + (kq * 4 + r) * 40] = f2bf(fmaxf(m1[m][r], 0.0f));
    }
    if (i >= 2 && t < 256){ // head(i-2): o2s . Wout
      int r = t >> 3, jj = t & 7;
      const float* orow = &o2s[r * 132 + jj * 16];
      const float* wrow = &WoutS[jj * 16];
      float s = 0.0f;
#pragma unroll
      for (int q = 0; q < 16; ++q) s += orow[q] * wrow[q];
      s += __shfl_down(s, 4, 8);
      s += __shfl_down(s, 2, 8);
      s += __shfl_down(s, 1, 8);
      if (jj == 0){
        float pv = s + bout0;
        out[(r0 + r) * T_STEPS + (i - 2)] = pv;
        pS[r] = pv;
      }
    }
    __syncthreads();

    // ---------------- PHASE B ----------------
    // gates(i): acc -> c,h; write h hi/lo panels
#pragma unroll
    for (int m = 0; m < 2; ++m)
#pragma unroll
      for (int r = 0; r < 4; ++r){
        float zi = acc[0][m][r], zf = acc[1][m][r], zg = acc[2][m][r], zo = acc[3][m][r];
        float c2 = sigm(zf) * cst[m * 4 + r] + sigm(zi) * tanh_(zg);
        cst[m * 4 + r] = c2;
        float h2 = sigm(zo) * tanh_(c2);
        int addr = wb + m * 640 + (kq * 4 + r) * 40;    // row = kq*4+r (C/D map)
        short hi = f2bf(h2);
        hhi[addr] = hi;
        hlo[addr] = f2bf(h2 - bf2f(hi));
      }
    if (i >= 1){ // MLP2(i-1): o1p -> o2s
      float4v m2[2];
#pragma unroll
      for (int m = 0; m < 2; ++m)
#pragma unroll
        for (int r = 0; r < 4; ++r) m2[m][r] = b2v;
#pragma unroll
      for (int ks = 0; ks < 4; ++ks){
#pragma unroll
        for (int m = 0; m < 2; ++m){
          short8 a = *(const short8*)&o1p[ks * 1280 + m * 640 + aoff];
          m2[m] = __builtin_amdgcn_mfma_f32_16x16x32_bf16(a, B2f[ks], m2[m], 0, 0, 0);
        }
      }
#pragma unroll
      for (int m = 0; m < 2; ++m)
#pragma unroll
        for (int r = 0; r < 4; ++r)
          o2s[(m * 16 + kq * 4 + r) * 132 + w * 16 + c16] = fmaxf(m2[m][r], 0.0f);
    }
    __syncthreads();
  }

  // =================== drain: MLP1(22)+head(21) | MLP2(22) | head(22) ======
  {
    float4v m1[2];
#pragma unroll
    for (int m = 0; m < 2; ++m)
#pragma unroll
      for (int r = 0; r < 4; ++r) m1[m][r] = b1v;
#pragma unroll
    for (int ks = 0; ks < 4; ++ks){
      short8 ah0 = *(const short8*)&hhi[ks * 1280 + aoff];
      short8 al0 = *(const short8*)&hlo[ks * 1280 + aoff];
      short8 ah1 = *(const short8*)&hhi[ks * 1280 + 640 + aoff];
      short8 al1 = *(const short8*)&hlo[ks * 1280 + 640 + aoff];
      m1[0] = __builtin_amdgcn_mfma_f32_16x16x32_bf16(ah0, B1f[ks], m1[0], 0, 0, 0);
      m1[0] = __builtin_amdgcn_mfma_f32_16x16x32_bf16(al0, B1f[ks], m1[0], 0, 0, 0);
      m1[1] = __builtin_amdgcn_mfma_f32_16x16x32_bf16(ah1, B1f[ks], m1[1], 0, 0, 0);
      m1[1] = __builtin_amdgcn_mfma_f32_16x16x32_bf16(al1, B1f[ks], m1[1], 0, 0, 0);
    }
#pragma unroll
    for (int m = 0; m < 2; ++m)
#pragma unroll
      for (int r = 0; r < 4; ++r)
        o1p[wb + m * 640 + (kq * 4 + r) * 40] = f2bf(fmaxf(m1[m][r], 0.0f));
    if (t < 256){ // head(21)
      int r = t >> 3, jj = t & 7;
      const float* orow = &o2s[r * 132 + jj * 16];
      const float* wrow = &WoutS[jj * 16];
      float s = 0.0f;
#pragma unroll
      for (int q = 0; q < 16; ++q) s += orow[q] * wrow[q];
      s += __shfl_down(s, 4, 8);
      s += __shfl_down(s, 2, 8);
      s += __shfl_down(s, 1, 8);
      if (jj == 0){
        float pv = s + bout0;
        out[(r0 + r) * T_STEPS + 21] = pv;
        pS[r] = pv;
      }
    }
    __syncthreads();
    // MLP2(22)
    float4v m2[2];
#pragma unroll
    for (int m = 0; m < 2; ++m)
#pragma unroll
      for (int r = 0; r < 4; ++r) m2[m][r] = b2v;
#pragma unroll
    for (int ks = 0; ks < 4; ++ks){
#pragma unroll
      for (int m = 0; m < 2; ++m){
        short8 a = *(const short8*)&o1p[ks * 1280 + m * 640 + aoff];
        m2[m] = __builtin_amdgcn_mfma_f32_16x16x32_bf16(a, B2f[ks], m2[m], 0, 0, 0);
      }
    }
#pragma unroll
    for (int m = 0; m < 2; ++m)
#pragma unroll
      for (int r = 0; r < 4; ++r)
        o2s[(m * 16 + kq * 4 + r) * 132 + w * 16 + c16] = fmaxf(m2[m][r], 0.0f);
    __syncthreads();
    if (t < 256){ // head(22)
      int r = t >> 3, jj = t & 7;
      const float* orow = &o2s[r * 132 + jj * 16];
      const float* wrow = &WoutS[jj * 16];
      float s = 0.0f;
#pragma unroll
      for (int q = 0; q < 16; ++q) s += orow[q] * wrow[q];
      s += __shfl_down(s, 4, 8);
      s += __shfl_down(s, 2, 8);
      s += __shfl_down(s, 1, 8);
      if (jj == 0){
        float pv = s + bout0;
        out[(r0 + r) * T_STEPS + 22] = pv;
        pS[r] = pv;
      }
    }
    __syncthreads();
  }

  // =================== serial tail: s = 23..29 (p feedback) ===============
  for (int s = 23; s < T_STEPS; ++s){
    if (s > 23){
      if (t < 256){ // gather(s) with autoregressive feedback
        int r = t >> 3, j = t & 7;
        float v = (j < 7) ? fp.f[j][(r0 + r) * T_STEPS + s] : pS[r];
        int base = (r >> 4) * 640 + (r & 15) * 40 + j;
        short hi = f2bf(v);
        short* xb = xp[s & 1];
        xb[base] = hi;
        xb[base + 8] = f2bf(v - bf2f(hi));
      }
      __syncthreads();
    }
    // z(s)
    float4v acc[4][2];
#pragma unroll
    for (int g = 0; g < 4; ++g)
#pragma unroll
      for (int m = 0; m < 2; ++m)
#pragma unroll
        for (int r = 0; r < 4; ++r) acc[g][m][r] = bzv[g];
    {
      const short* xb = xp[s & 1];
      short8 a0 = *(const short8*)&xb[aoff];
      short8 a1 = *(const short8*)&xb[640 + aoff];
#pragma unroll
      for (int g = 0; g < 4; ++g){
        acc[g][0] = __builtin_amdgcn_mfma_f32_16x16x32_bf16(a0, Bz[g][0], acc[g][0], 0, 0, 0);
        acc[g][1] = __builtin_amdgcn_mfma_f32_16x16x32_bf16(a1, Bz[g][0], acc[g][1], 0, 0, 0);
      }
    }
#pragma unroll
    for (int ks = 0; ks < 4; ++ks){
      short8 ah0 = *(const short8*)&hhi[ks * 1280 + aoff];
      short8 al0 = *(const short8*)&hlo[ks * 1280 + aoff];
      short8 ah1 = *(const short8*)&hhi[ks * 1280 + 640 + aoff];
      short8 al1 = *(const short8*)&hlo[ks * 1280 + 640 + aoff];
#pragma unroll
      for (int g = 0; g < 4; ++g){
        acc[g][0] = __builtin_amdgcn_mfma_f32_16x16x32_bf16(ah0, Bz[g][1 + ks], acc[g][0], 0, 0, 0);
        acc[g][0] = __builtin_amdgcn_mfma_f32_16x16x32_bf16(al0, Bz[g][1 + ks], acc[g][0], 0, 0, 0);
        acc[g][1] = __builtin_amdgcn_mfma_f32_16x16x32_bf16(ah1, Bz[g][1 + ks], acc[g][1], 0, 0, 0);
        acc[g][1] = __builtin_amdgcn_mfma_f32_16x16x32_bf16(al1, Bz[g][1 + ks], acc[g][1], 0, 0, 0);
      }
    }
    __syncthreads();
    // gates(s)
#pragma unroll
    for (int m = 0; m < 2; ++m)
#pragma unroll
      for (int r = 0; r < 4; ++r){
        float zi = acc[0][m][r], zf = acc[1][m][r], zg = acc[2][m][r], zo = acc[3][m][r];
        float c2 = sigm(zf) * cst[m * 4 + r] + sigm(zi) * tanh_(zg);
        cst[m * 4 + r] = c2;
        float h2 = sigm(zo) * tanh_(c2);
        int addr = wb + m * 640 + (kq * 4 + r) * 40;
        short hi = f2bf(h2);
        hhi[addr] = hi;
        hlo[addr] = f2bf(h2 - bf2f(hi));
      }
    __syncthreads();
    // MLP1(s)
    float4v m1[2];
#pragma unroll
    for (int m = 0; m < 2; ++m)
#pragma unroll
      for (int r = 0; r < 4; ++r) m1[m][r] = b1v;
#pragma unroll
    for (int ks = 0; ks < 4; ++ks){
      short8 ah0 = *(const short8*)&hhi[ks * 1280 + aoff];
      short8 al0 = *(const short8*)&hlo[ks * 1280 + aoff];
      short8 ah1 = *(const short8*)&hhi[ks * 1280 + 640 + aoff];
      short8 al1 = *(const short8*)&hlo[ks * 1280 + 640 + aoff];
      m1[0] = __builtin_amdgcn_mfma_f32_16x16x32_bf16(ah0, B1f[ks], m1[0], 0, 0, 0);
      m1[0] = __builtin_amdgcn_mfma_f32_16x16x32_bf16(al0, B1f[ks], m1[0], 0, 0, 0);
      m1[1] = __builtin_amdgcn_mfma_f32_16x16x32_bf16(ah1, B1f[ks], m1[1], 0, 0, 0);
      m1[1] = __builtin_amdgcn_mfma_f32_16x16x32_bf16(al1, B1f[ks], m1[1], 0, 0, 0);
    }
#pragma unroll
    for (int m = 0; m < 2; ++m)
#pragma unroll
      for (int r = 0; r < 4; ++r)
        o1p[wb + m * 640 + (kq * 4 + r) * 40] = f2bf(fmaxf(m1[m][r], 0.0f));
    __syncthreads();
    // MLP2(s)
    float4v m2[2];
#pragma unroll
    for (int m = 0; m < 2; ++m)
#pragma unroll
      for (int r = 0; r < 4; ++r) m2[m][r] = b2v;
#pragma unroll
    for (int ks = 0; ks < 4; ++ks){
#pragma unroll
      for (int m = 0; m < 2; ++m){
        short8 a = *(const short8*)&o1p[ks * 1280 + m * 640 + aoff];
        m2[m] = __builtin_amdgcn_mfma_f32_16x16x32_bf16(a, B2f[ks], m2[m], 0, 0, 0);
      }
    }
#pragma unroll
    for (int m = 0; m < 2; ++m)
#pragma unroll
      for (int r = 0; r < 4; ++r)
        o2s[(m * 16 + kq * 4 + r) * 132 + w * 16 + c16] = fmaxf(m2[m][r], 0.0f);
    __syncthreads();
    // head(s)
    if (t < 256){
      int r = t >> 3, jj = t & 7;
      const float* orow = &o2s[r * 132 + jj * 16];
      const float* wrow = &WoutS[jj * 16];
      float ssum = 0.0f;
#pragma unroll
      for (int q = 0; q < 16; ++q) ssum += orow[q] * wrow[q];
      ssum += __shfl_down(ssum, 4, 8);
      ssum += __shfl_down(ssum, 2, 8);
      ssum += __shfl_down(ssum, 1, 8);
      if (jj == 0){
        float pv = ssum + bout0;
        out[(r0 + r) * T_STEPS + s] = pv;
        pS[r] = pv;
      }
    }
    __syncthreads();
  }
}

extern "C" void kernel_launch(void* const* d_in, const int* in_sizes, int n_in,
                              void* d_out, int out_size, void* d_ws, size_t ws_size,
                              hipStream_t stream)
{
  (void)in_sizes; (void)n_in; (void)out_size; (void)ws_size;
  // inputs: 0..7 weather (unused), 8..14 time feats, 15 irradiance_in,
  // 16 Wi, 17 Wh, 18 b, 19 W1, 20 b1, 21 W2, 22 b2, 23 Wout, 24 bout
  FeatPtrs fp;
  for (int j = 0; j < 7; ++j) fp.f[j] = (const float*)d_in[8 + j];
  const float* irr  = (const float*)d_in[15];
  const float* Wi   = (const float*)d_in[16];
  const float* Wh   = (const float*)d_in[17];
  const float* bz   = (const float*)d_in[18];
  const float* W1   = (const float*)d_in[19];
  const float* b1   = (const float*)d_in[20];
  const float* W2   = (const float*)d_in[21];
  const float* b2   = (const float*)d_in[22];
  const float* Wout = (const float*)d_in[23];
  const float* bout = (const float*)d_in[24];

  short* ws = (short*)d_ws;                       // 224*512*2 = 224 KB used
  pack_weights<<<dim3(448), dim3(256), 0, stream>>>(Wi, Wh, W1, W2, ws);
  lstm_mfma<<<dim3(256), dim3(512), 0, stream>>>(
      fp, irr, ws, bz, b1, b2, Wout, bout, (float*)d_out);
}

// Round 7
// 182.335 us; speedup vs baseline: 2.5793x; 1.1284x over previous
//
#include <hip/hip_runtime.h>

// Fused LSTM(H=128) + 3-layer MLP head, fp16 MFMA (16x16x32), fp32 state.
// B=8192 rows, T=30 steps. 256 blocks x 512 threads (8 waves), 32 rows/block.
// ROUND 7: r6 measured 79% pipe-busy (MfmaUtil 34 + VALUBusy 45) at 2
// waves/SIMD (grid caps occupancy at 25%; r4/r5 proved more is reg-infeasible).
// So REDUCE pipe work:
//  (a) fp16 single replaces bf16 hi/lo everywhere (x, h, o1, weights):
//      halves z/MLP1 MFMA count (104->56 per wave-step) and cuts VALU
//      epilogues (1-op v_cvt_f16_f32, no lo pass). fp16 11-bit mantissa:
//      h error ~2^-12/step; weights/o1 get MORE precise than bf16 (2^-11/-12
//      vs 2^-9), which were the absmax-dominating terms.
//  (b) tail (steps 23..29) restructured like warm: MLP(s-1) trails z(s),
//      MLP1 fused on z's h-panel reads, 4 barriers/step (was 6), gather
//      off critical path; p feedback injected via VALU (acc += p*Wi[7][col],
//      j7 LDS slot zeroed) instead of a gather barrier + x-refill.
// - Wave w owns output cols [16w,16w+16); 2 M-tiles (rows 0-15,16-31).
// - x-frag: K slots 0..7 = 8 features, 8..31 zero.
// - 16x16x32 layouts: A/B: row|col=lane&15, k=(lane>>4)*8+j; C/D: col=lane&15,
//   row=(lane>>4)*4+reg (m89-verified, dtype-independent).
// - A-panels [16 rows][40 halfs] (32 data + 8 pad): 16B-aligned b128 reads.
// - fp32: accumulators, c-state, gates, o2, head, feedback p.

#define T_STEPS 30
#define WARM_N  24

typedef _Float16 h8 __attribute__((ext_vector_type(8)));     // 8 fp16 = 4 VGPRs
typedef __attribute__((ext_vector_type(4))) float float4v;   // MFMA 16x16 C/D

struct FeatPtrs { const float* f[7]; };

#if __has_builtin(__builtin_amdgcn_rcpf)
#define RCP(x) __builtin_amdgcn_rcpf(x)
#else
#define RCP(x) (1.0f/(x))
#endif

__device__ __forceinline__ float sigm(float x){ return RCP(1.0f + __expf(-x)); }
__device__ __forceinline__ float tanh_(float x){ return 1.0f - 2.0f*RCP(1.0f + __expf(2.0f*x)); }

// ---------------- weight pack kernel ----------------
// 224 frags of 512 fp16 (1 KB each), frag elem (lane,j):
//   col16 = lane&15, kk = (lane>>4)*8 + j  (K=32 per fragment)
// frags 0..159 : z-weights [wt 0..7][g 0..3][ks 0..4]
//   ks=0: x-frag: kk<8 -> Wi[kk][col], kk>=8 -> 0
//   ks 1..4: Wh[(ks-1)*32+kk][col];  col = g*128+wt*16+col16
// frags 160..191: W1 [wt][ks 0..3]: W1[ks*32+kk][wt*16+col16]
// frags 192..223: W2 same layout.
__global__ void pack_weights(const float* __restrict__ Wi, const float* __restrict__ Wh,
                             const float* __restrict__ W1, const float* __restrict__ W2,
                             _Float16* __restrict__ ws)
{
  int idx = blockIdx.x * 256 + threadIdx.x;
  if (idx >= 224 * 512) return;
  int f    = idx >> 9;
  int r    = idx & 511;
  int lane = r >> 3, j = r & 7;
  int kk   = ((lane >> 4) << 3) + j;     // 0..31
  int c16  = lane & 15;
  float v = 0.0f;
  if (f < 160){
    int wt = f / 20, rem = f % 20, g = rem / 5, ks = rem % 5;
    int col = g * 128 + wt * 16 + c16;
    if (ks == 0) v = (kk < 8) ? Wi[kk * 512 + col] : 0.0f;
    else         v = Wh[((ks - 1) * 32 + kk) * 512 + col];
  } else {
    int f2 = f - 160;                    // 0..63
    const float* W = (f2 < 32) ? W1 : W2;
    int f3 = f2 & 31;
    int wt = f3 >> 2, ks = f3 & 3;
    v = W[(ks * 32 + kk) * 128 + wt * 16 + c16];
  }
  ws[idx] = (_Float16)v;
}

// ---------------- head: p = o2 . Wout + bout (fp32 exact) ----------------
__device__ __forceinline__ void head_do(int t, int r0, int step,
    const float* o2s, const float* WoutS, float bout0,
    float* __restrict__ out, float* pS)
{
  if (t < 256){
    int r = t >> 3, jj = t & 7;
    const float* orow = &o2s[r * 132 + jj * 16];
    const float* wrow = &WoutS[jj * 16];
    float s = 0.0f;
#pragma unroll
    for (int q = 0; q < 16; ++q) s += orow[q] * wrow[q];
    s += __shfl_down(s, 4, 8);
    s += __shfl_down(s, 2, 8);
    s += __shfl_down(s, 1, 8);
    if (jj == 0){
      float pv = s + bout0;
      out[(r0 + r) * T_STEPS + step] = pv;
      pS[r] = pv;
    }
  }
}

#define MFMA16 __builtin_amdgcn_mfma_f32_16x16x32_f16

// ---------------- main kernel ----------------
__global__ __launch_bounds__(512, 2)
void lstm_mfma(FeatPtrs fp, const float* __restrict__ irr,
               const _Float16* __restrict__ wsb,
               const float* __restrict__ bz, const float* __restrict__ b1,
               const float* __restrict__ b2, const float* __restrict__ Wout,
               const float* __restrict__ bout, float* __restrict__ out)
{
  // A-panels: [m-tile 0..1][16 rows][40 halfs] (k 0..31 data + 8 pad)
  __shared__ __align__(16) _Float16 xp[2][1280];    // x, double-buffered steps
  __shared__ __align__(16) _Float16 hp [4 * 1280];  // h, 4 ksteps
  __shared__ __align__(16) _Float16 o1p[4 * 1280];  // o1, 4 ksteps
  __shared__ __align__(16) float o2s[32 * 132];     // o2 fp32, padded rows
  __shared__ float WoutS[128];
  __shared__ float pS[32];

  const int t   = threadIdx.x;
  const int l   = t & 63;
  const int w   = t >> 6;        // wave 0..7, owns cols [16w,16w+16)
  const int c16 = l & 15;
  const int kq  = l >> 4;        // 0..3
  const int r0  = blockIdx.x * 32;

  // weight fragments -> registers (112 VGPRs, same footprint as r6)
  h8 Bz[4][5], B1f[4], B2f[4];
  {
    const h8* f8 = (const h8*)wsb;
#pragma unroll
    for (int g = 0; g < 4; ++g)
#pragma unroll
      for (int ks = 0; ks < 5; ++ks)
        Bz[g][ks] = f8[((w * 4 + g) * 5 + ks) * 64 + l];
#pragma unroll
    for (int ks = 0; ks < 4; ++ks) B1f[ks] = f8[(160 + w * 4 + ks) * 64 + l];
#pragma unroll
    for (int ks = 0; ks < 4; ++ks) B2f[ks] = f8[(192 + w * 4 + ks) * 64 + l];
  }
  float bzv[4], wi7[4];
#pragma unroll
  for (int g = 0; g < 4; ++g){
    bzv[g] = bz[g * 128 + w * 16 + c16];
    // Wi[7][col] as the SAME fp16 value the x-MFMA would use (frag elem kk=7)
    wi7[g] = (float)wsb[((w * 4 + g) * 5) * 512 + c16 * 8 + 7];
  }
  const float b1v   = b1[w * 16 + c16];
  const float b2v   = b2[w * 16 + c16];
  const float bout0 = bout[0];
  if (t < 128) WoutS[t] = Wout[t];

  { // zero x buffers (k8..31 must stay 0) and h panels (h0 = 0)
    int* p = (int*)xp;
    for (int i = t; i < 1280; i += 512) p[i] = 0;
    p = (int*)hp;
    for (int i = t; i < 2560; i += 512) p[i] = 0;
  }

  float cst[8];
#pragma unroll
  for (int i = 0; i < 8; ++i) cst[i] = 0.0f;

  const int aoff = c16 * 40 + kq * 8;                    // A-frag read offset
  const int wb   = (w >> 1) * 1280 + (w & 1) * 16 + c16; // h/o1 write base
  __syncthreads();

  // prologue: gather step 0 into xp[0]
  if (t < 256){
    int r = t >> 3, j = t & 7;
    float v = (j < 7) ? fp.f[j][(r0 + r) * T_STEPS] : irr[(r0 + r) * WARM_N];
    xp[0][(r >> 4) * 640 + (r & 15) * 40 + j] = (_Float16)v;
  }
  __syncthreads();

  // =================== pipelined warm loop: i = 0..22 ===================
  for (int i = 0; i < 23; ++i){
    // ---------------- PHASE A ----------------
    if (t < 256){ // gather(i+1): i+1 <= 23 < WARM_N -> always irr for j==7
      int r = t >> 3, j = t & 7;
      float v = (j < 7) ? fp.f[j][(r0 + r) * T_STEPS + (i + 1)]
                        : irr[(r0 + r) * WARM_N + (i + 1)];
      xp[(i + 1) & 1][(r >> 4) * 640 + (r & 15) * 40 + j] = (_Float16)v;
    }
    // z(i) + MLP1(i-1), fused on shared h-panel reads
    float4v acc[4][2];
#pragma unroll
    for (int g = 0; g < 4; ++g)
#pragma unroll
      for (int m = 0; m < 2; ++m)
#pragma unroll
        for (int r = 0; r < 4; ++r) acc[g][m][r] = bzv[g];
    float4v m1[2];
#pragma unroll
    for (int m = 0; m < 2; ++m)
#pragma unroll
      for (int r = 0; r < 4; ++r) m1[m][r] = b1v;
    {
      const _Float16* xb = xp[i & 1];
      h8 a0 = *(const h8*)&xb[aoff];
      h8 a1 = *(const h8*)&xb[640 + aoff];
#pragma unroll
      for (int g = 0; g < 4; ++g){
        acc[g][0] = MFMA16(a0, Bz[g][0], acc[g][0], 0, 0, 0);
        acc[g][1] = MFMA16(a1, Bz[g][0], acc[g][1], 0, 0, 0);
      }
    }
#pragma unroll
    for (int ks = 0; ks < 4; ++ks){
      h8 ah0 = *(const h8*)&hp[ks * 1280 + aoff];
      h8 ah1 = *(const h8*)&hp[ks * 1280 + 640 + aoff];
#pragma unroll
      for (int g = 0; g < 4; ++g){
        acc[g][0] = MFMA16(ah0, Bz[g][1 + ks], acc[g][0], 0, 0, 0);
        acc[g][1] = MFMA16(ah1, Bz[g][1 + ks], acc[g][1], 0, 0, 0);
      }
      if (i >= 1){
        m1[0] = MFMA16(ah0, B1f[ks], m1[0], 0, 0, 0);
        m1[1] = MFMA16(ah1, B1f[ks], m1[1], 0, 0, 0);
      }
    }
    if (i >= 1){ // write o1p(i-1)
#pragma unroll
      for (int m = 0; m < 2; ++m)
#pragma unroll
        for (int r = 0; r < 4; ++r)
          o1p[wb + m * 640 + (kq * 4 + r) * 40] = (_Float16)fmaxf(m1[m][r], 0.0f);
    }
    if (i >= 2) head_do(t, r0, i - 2, o2s, WoutS, bout0, out, pS);
    __syncthreads();

    // ---------------- PHASE B ----------------
    // gates(i): acc -> c,h; write h panels (single fp16)
#pragma unroll
    for (int m = 0; m < 2; ++m)
#pragma unroll
      for (int r = 0; r < 4; ++r){
        float zi = acc[0][m][r], zf = acc[1][m][r], zg = acc[2][m][r], zo = acc[3][m][r];
        float c2 = sigm(zf) * cst[m * 4 + r] + sigm(zi) * tanh_(zg);
        cst[m * 4 + r] = c2;
        float h2 = sigm(zo) * tanh_(c2);
        hp[wb + m * 640 + (kq * 4 + r) * 40] = (_Float16)h2;  // row = kq*4+r
      }
    if (i >= 1){ // MLP2(i-1): o1p -> o2s
      float4v m2[2];
#pragma unroll
      for (int m = 0; m < 2; ++m)
#pragma unroll
        for (int r = 0; r < 4; ++r) m2[m][r] = b2v;
#pragma unroll
      for (int ks = 0; ks < 4; ++ks){
        h8 a0 = *(const h8*)&o1p[ks * 1280 + aoff];
        h8 a1 = *(const h8*)&o1p[ks * 1280 + 640 + aoff];
        m2[0] = MFMA16(a0, B2f[ks], m2[0], 0, 0, 0);
        m2[1] = MFMA16(a1, B2f[ks], m2[1], 0, 0, 0);
      }
#pragma unroll
      for (int m = 0; m < 2; ++m)
#pragma unroll
        for (int r = 0; r < 4; ++r)
          o2s[(m * 16 + kq * 4 + r) * 132 + w * 16 + c16] = fmaxf(m2[m][r], 0.0f);
    }
    __syncthreads();
  }

  // ============ P0: head(21) (o2s(21) written in warm i=22 phase B) ========
  head_do(t, r0, 21, o2s, WoutS, bout0, out, pS);
  __syncthreads();

  // ===== pipelined tail: s = 23..29, MLP(s-1) trails z(s), 4 barriers ======
  for (int s = 23; s < T_STEPS; ++s){
    // ---- TA: gather feats(s+1) (j7<-0, p injected later) | z(s) + MLP1(s-1)
    if (s < T_STEPS - 1 && t < 256){
      int r = t >> 3, j = t & 7;
      float v = (j < 7) ? fp.f[j][(r0 + r) * T_STEPS + (s + 1)] : 0.0f;
      xp[(s + 1) & 1][(r >> 4) * 640 + (r & 15) * 40 + j] = (_Float16)v;
    }
    float4v acc[4][2];
#pragma unroll
    for (int g = 0; g < 4; ++g)
#pragma unroll
      for (int m = 0; m < 2; ++m)
#pragma unroll
        for (int r = 0; r < 4; ++r) acc[g][m][r] = bzv[g];
    float4v m1[2];
#pragma unroll
    for (int m = 0; m < 2; ++m)
#pragma unroll
      for (int r = 0; r < 4; ++r) m1[m][r] = b1v;
    {
      const _Float16* xb = xp[s & 1];   // s=23: j7=irr[23] (real); s>23: j7=0
      h8 a0 = *(const h8*)&xb[aoff];
      h8 a1 = *(const h8*)&xb[640 + aoff];
#pragma unroll
      for (int g = 0; g < 4; ++g){
        acc[g][0] = MFMA16(a0, Bz[g][0], acc[g][0], 0, 0, 0);
        acc[g][1] = MFMA16(a1, Bz[g][0], acc[g][1], 0, 0, 0);
      }
    }
#pragma unroll
    for (int ks = 0; ks < 4; ++ks){
      h8 ah0 = *(const h8*)&hp[ks * 1280 + aoff];
      h8 ah1 = *(const h8*)&hp[ks * 1280 + 640 + aoff];
#pragma unroll
      for (int g = 0; g < 4; ++g){
        acc[g][0] = MFMA16(ah0, Bz[g][1 + ks], acc[g][0], 0, 0, 0);
        acc[g][1] = MFMA16(ah1, Bz[g][1 + ks], acc[g][1], 0, 0, 0);
      }
      m1[0] = MFMA16(ah0, B1f[ks], m1[0], 0, 0, 0);
      m1[1] = MFMA16(ah1, B1f[ks], m1[1], 0, 0, 0);
    }
#pragma unroll
    for (int m = 0; m < 2; ++m)
#pragma unroll
      for (int r = 0; r < 4; ++r)
        o1p[wb + m * 640 + (kq * 4 + r) * 40] = (_Float16)fmaxf(m1[m][r], 0.0f);
    __syncthreads();

    // ---- TB: MLP2(s-1) ----
    {
      float4v m2[2];
#pragma unroll
      for (int m = 0; m < 2; ++m)
#pragma unroll
        for (int r = 0; r < 4; ++r) m2[m][r] = b2v;
#pragma unroll
      for (int ks = 0; ks < 4; ++ks){
        h8 a0 = *(const h8*)&o1p[ks * 1280 + aoff];
        h8 a1 = *(const h8*)&o1p[ks * 1280 + 640 + aoff];
        m2[0] = MFMA16(a0, B2f[ks], m2[0], 0, 0, 0);
        m2[1] = MFMA16(a1, B2f[ks], m2[1], 0, 0, 0);
      }
#pragma unroll
      for (int m = 0; m < 2; ++m)
#pragma unroll
        for (int r = 0; r < 4; ++r)
          o2s[(m * 16 + kq * 4 + r) * 132 + w * 16 + c16] = fmaxf(m2[m][r], 0.0f);
    }
    __syncthreads();

    // ---- TC: head(s-1) -> out, pS ----
    head_do(t, r0, s - 1, o2s, WoutS, bout0, out, pS);
    __syncthreads();

    // ---- TD: p-inject (s>=24) + gates(s) -> hp ----
    if (s >= 24){
#pragma unroll
      for (int m = 0; m < 2; ++m)
#pragma unroll
        for (int r = 0; r < 4; ++r){
          float pv = pS[m * 16 + kq * 4 + r];
#pragma unroll
          for (int g = 0; g < 4; ++g) acc[g][m][r] += pv * wi7[g];
        }
    }
#pragma unroll
    for (int m = 0; m < 2; ++m)
#pragma unroll
      for (int r = 0; r < 4; ++r){
        float zi = acc[0][m][r], zf = acc[1][m][r], zg = acc[2][m][r], zo = acc[3][m][r];
        float c2 = sigm(zf) * cst[m * 4 + r] + sigm(zi) * tanh_(zg);
        cst[m * 4 + r] = c2;
        float h2 = sigm(zo) * tanh_(c2);
        hp[wb + m * 640 + (kq * 4 + r) * 40] = (_Float16)h2;
      }
    __syncthreads();
  }

  // =================== final drain: MLP1(29) | MLP2(29) | head(29) =========
  {
    float4v m1[2];
#pragma unroll
    for (int m = 0; m < 2; ++m)
#pragma unroll
      for (int r = 0; r < 4; ++r) m1[m][r] = b1v;
#pragma unroll
    for (int ks = 0; ks < 4; ++ks){
      h8 ah0 = *(const h8*)&hp[ks * 1280 + aoff];
      h8 ah1 = *(const h8*)&hp[ks * 1280 + 640 + aoff];
      m1[0] = MFMA16(ah0, B1f[ks], m1[0], 0, 0, 0);
      m1[1] = MFMA16(ah1, B1f[ks], m1[1], 0, 0, 0);
    }
#pragma unroll
    for (int m = 0; m < 2; ++m)
#pragma unroll
      for (int r = 0; r < 4; ++r)
        o1p[wb + m * 640 + (kq * 4 + r) * 40] = (_Float16)fmaxf(m1[m][r], 0.0f);
    __syncthreads();
    float4v m2[2];
#pragma unroll
    for (int m = 0; m < 2; ++m)
#pragma unroll
      for (int r = 0; r < 4; ++r) m2[m][r] = b2v;
#pragma unroll
    for (int ks = 0; ks < 4; ++ks){
      h8 a0 = *(const h8*)&o1p[ks * 1280 + aoff];
      h8 a1 = *(const h8*)&o1p[ks * 1280 + 640 + aoff];
      m2[0] = MFMA16(a0, B2f[ks], m2[0], 0, 0, 0);
      m2[1] = MFMA16(a1, B2f[ks], m2[1], 0, 0, 0);
    }
#pragma unroll
    for (int m = 0; m < 2; ++m)
#pragma unroll
      for (int r = 0; r < 4; ++r)
        o2s[(m * 16 + kq * 4 + r) * 132 + w * 16 + c16] = fmaxf(m2[m][r], 0.0f);
    __syncthreads();
    head_do(t, r0, 29, o2s, WoutS, bout0, out, pS);
  }
}

extern "C" void kernel_launch(void* const* d_in, const int* in_sizes, int n_in,
                              void* d_out, int out_size, void* d_ws, size_t ws_size,
                              hipStream_t stream)
{
  (void)in_sizes; (void)n_in; (void)out_size; (void)ws_size;
  // inputs: 0..7 weather (unused), 8..14 time feats, 15 irradiance_in,
  // 16 Wi, 17 Wh, 18 b, 19 W1, 20 b1, 21 W2, 22 b2, 23 Wout, 24 bout
  FeatPtrs fp;
  for (int j = 0; j < 7; ++j) fp.f[j] = (const float*)d_in[8 + j];
  const float* irr  = (const float*)d_in[15];
  const float* Wi   = (const float*)d_in[16];
  const float* Wh   = (const float*)d_in[17];
  const float* bz   = (const float*)d_in[18];
  const float* W1   = (const float*)d_in[19];
  const float* b1   = (const float*)d_in[20];
  const float* W2   = (const float*)d_in[21];
  const float* b2   = (const float*)d_in[22];
  const float* Wout = (const float*)d_in[23];
  const float* bout = (const float*)d_in[24];

  _Float16* ws = (_Float16*)d_ws;                 // 224*512*2 = 224 KB used
  pack_weights<<<dim3(448), dim3(256), 0, stream>>>(Wi, Wh, W1, W2, ws);
  lstm_mfma<<<dim3(256), dim3(512), 0, stream>>>(
      fp, irr, ws, bz, b1, b2, Wout, bout, (float*)d_out);
}